// Round 6
// baseline (805.207 us; speedup 1.0000x reference)
//
#include <hip/hip_runtime.h>
#include <math.h>

// C=48, DM=24, DIN=48, DS=8, DC=4, DTR=2, B=2, D=H=W=32, L=32768
#define LL   32768
#define NCH  1024          // scan chunks per sequence
#define LC   32            // chunk length
#define BL48 3145728       // B*48*L floats == 2*48*LL
#define ROW48(g,l) (((size_t)(g)*LL + (l))*48)
#define ROW16(g,l) (((size_t)(g)*LL + (l))*16)

typedef unsigned short ushort_t;
typedef ushort_t ushort8 __attribute__((ext_vector_type(8)));

__device__ __forceinline__ float sigmoidf_(float x){ return 1.0f/(1.0f+__expf(-x)); }
__device__ __forceinline__ float softplusf_(float x){ return (x > 20.0f) ? x : log1pf(__expf(x)); }
__device__ __forceinline__ ushort_t f2bf(float f){
  union { float f; unsigned u; } v; v.f = f;
  unsigned r = v.u + 0x7FFFu + ((v.u >> 16) & 1u);
  return (ushort_t)(r >> 16);
}
__device__ __forceinline__ float bf2f(ushort_t h){
  union { unsigned u; float f; } v; v.u = ((unsigned)h) << 16;
  return v.f;
}

// ---------------------------------------------------------------------------
// LN + in-proj (96x24 GEMV), thread per (l, dir, e-half). No LDS, no sync.
// Writes pre-conv xz bf16 [b][l][96] per dir (x in 0..47, raw z in 48..95).
// ---------------------------------------------------------------------------
extern "C" __global__ void __launch_bounds__(256)
k_inproj(const float* __restrict__ cur,
         const float* __restrict__ lng, const float* __restrict__ lnb,
         const float* __restrict__ in_w,
         ushort_t* __restrict__ xzF, ushort_t* __restrict__ xzB, int orient)
{
  const int l   = blockIdx.x*256 + threadIdx.x;
  const int b   = blockIdx.y;
  const int dir = blockIdx.z >> 1;
  const int eh  = blockIdx.z & 1;
  const int j   = 2*orient + dir;
  const int ch0 = dir*24;
  const float* iw = in_w + j*2304;   // (96,24)

  // LayerNorm over 48 channels
  const float* p = cur + (size_t)b*48*LL + l;
  float v[48]; float mu = 0.f;
  #pragma unroll
  for (int c2 = 0; c2 < 48; c2++){ v[c2] = p[(size_t)c2*LL]; mu += v[c2]; }
  mu *= (1.f/48.f);
  float var = 0.f;
  #pragma unroll
  for (int c2 = 0; c2 < 48; c2++){ float dd = v[c2]-mu; var += dd*dd; }
  float rstd = rsqrtf(var*(1.f/48.f) + 1e-5f);
  float u[24];
  #pragma unroll
  for (int c2 = 0; c2 < 24; c2++)
    u[c2] = (v[ch0+c2]-mu)*rstd*lng[ch0+c2] + lnb[ch0+c2];

  ushort_t* xr = (dir ? xzB : xzF) + ((size_t)b*LL + l)*96;
  const int e0b = eh*48;
  for (int e0 = e0b; e0 < e0b+48; e0 += 8){
    ushort8 o;
    #pragma unroll
    for (int k = 0; k < 8; k++){
      float s = 0.f;
      #pragma unroll
      for (int d = 0; d < 24; d++) s += u[d]*iw[(e0+k)*24+d];
      o[k] = f2bf(s);
    }
    *(ushort8*)(xr + e0) = o;
  }
}

// ---------------------------------------------------------------------------
// conv + silu + x-proj + dt(softplus) + FUSED scan phase 1.
// tile = 64 positions (= 2 chunks), block 192, one (b,dir) per blockIdx.{y,z}.
// Phase A (128 thr): per (pos, d-half) conv from global xz rows, silu, xc,
// xd partials (2-way LDS reduce), dt, B/C. Stores bf16 global + LDS stage.
// Phase B (192 thr = 2 chunks x 48 d x 2 s-halves): in-LDS chunk scan ->
// P,S written to PS fp32 [g][c][768] (P at d*8+s, S at +384).
// ---------------------------------------------------------------------------
extern "C" __global__ void __launch_bounds__(192)
k_convscan(const ushort_t* __restrict__ xzF, const ushort_t* __restrict__ xzB,
           const float* __restrict__ conv_w, const float* __restrict__ conv_b,
           const float* __restrict__ xproj_w, const float* __restrict__ dt_w,
           const float* __restrict__ dt_b, const float* __restrict__ A_log,
           ushort_t* __restrict__ dtb, ushort_t* __restrict__ xcb,
           ushort_t* __restrict__ BCB, float* __restrict__ PS, int orient)
{
  __shared__ ushort_t sdt[64][48];
  __shared__ ushort_t sxc[64][48];
  __shared__ ushort_t sbc[64][16];
  __shared__ float red[64][2][19];
  const int t   = threadIdx.x;
  const int b   = blockIdx.y;
  const int dir = blockIdx.z;
  const int bs  = blockIdx.x*64;
  const int j   = 2*orient + dir;
  const int g   = 2*dir + b;
  const ushort_t* xz = dir ? xzB : xzF;

  float xd[18];
  int p=0, half=0, d0=0, pos=0;
  if (t < 128){
    p = t & 63; half = t >> 6; d0 = half*24;
    const int l = bs + p;
    pos = dir ? (LL-1-l) : l;
    const float* cw = conv_w + j*192;   // (48,4)
    const float* cb = conv_b + j*48;
    const float* xw = xproj_w + j*864;  // (18,48)
    // load 4 xz rows x 24 cols (bf16)
    float xr[4][24];
    const int base = dir ? l : (l-3);
    #pragma unroll
    for (int rr = 0; rr < 4; rr++){
      int row = base + rr;
      if (row >= 0 && row < LL){
        const ushort_t* rp = xz + ((size_t)b*LL + row)*96 + d0;
        ushort8 a0 = *(const ushort8*)(rp);
        ushort8 a1 = *(const ushort8*)(rp+8);
        ushort8 a2 = *(const ushort8*)(rp+16);
        #pragma unroll
        for (int k = 0; k < 8; k++){
          xr[rr][k]    = bf2f(a0[k]);
          xr[rr][8+k]  = bf2f(a1[k]);
          xr[rr][16+k] = bf2f(a2[k]);
        }
      } else {
        #pragma unroll
        for (int k = 0; k < 24; k++) xr[rr][k] = 0.f;
      }
    }
    #pragma unroll
    for (int q = 0; q < 18; q++) xd[q]=0.f;
    float xcv[24];
    for (int dd = 0; dd < 24; dd++){
      int d = d0 + dd;
      float acc = cb[d];
      #pragma unroll
      for (int kk = 0; kk < 4; kk++){
        int rr = dir ? (3-kk) : kk;
        acc += xr[rr][dd] * cw[d*4+kk];
      }
      acc = acc * sigmoidf_(acc);   // silu
      xcv[dd] = acc;
      #pragma unroll
      for (int q = 0; q < 18; q++) xd[q] += acc*xw[q*48+d];
    }
    #pragma unroll
    for (int q = 0; q < 18; q++) red[p][half][q] = xd[q];
    // xc -> global + LDS stage
    ushort_t* xcr = xcb + ROW48(g, pos) + d0;
    #pragma unroll
    for (int q8 = 0; q8 < 24; q8 += 8){
      ushort8 o;
      #pragma unroll
      for (int k = 0; k < 8; k++) o[k] = f2bf(xcv[q8+k]);
      *(ushort8*)(xcr + q8) = o;
      *(ushort8*)(&sxc[p][d0+q8]) = o;
    }
  }
  __syncthreads();
  if (t < 128){
    #pragma unroll
    for (int q = 0; q < 18; q++) xd[q] += red[p][1-half][q];
    // dt
    const float* dw = dt_w + j*96;  // (48,2)
    const float* db = dt_b + j*48;
    ushort_t* dtr = dtb + ROW48(g, pos) + d0;
    #pragma unroll
    for (int q8 = 0; q8 < 24; q8 += 8){
      ushort8 o;
      #pragma unroll
      for (int k = 0; k < 8; k++){
        int d = d0 + q8 + k;
        o[k] = f2bf(softplusf_(xd[0]*dw[d*2] + xd[1]*dw[d*2+1] + db[d]));
      }
      *(ushort8*)(dtr + q8) = o;
      *(ushort8*)(&sdt[p][d0+q8]) = o;
    }
    // B/C: half0 -> B (xd[2..9]) cols 0..7, half1 -> C (xd[10..17]) cols 8..15
    ushort8 o;
    #pragma unroll
    for (int k = 0; k < 8; k++) o[k] = f2bf(xd[2+half*8+k]);
    *(ushort8*)(BCB + ROW16(g, pos) + half*8) = o;
    *(ushort8*)(&sbc[p][half*8]) = o;
  }
  __syncthreads();

  // ---- fused scan1: 2 chunks x 48 d x 2 s-halves ----
  {
    const int ck = t/96, r = t%96, d = r%48, sh = (r/48)*4;
    const int c = dir ? ((LL-64-bs)/32 + ck) : (bs/32 + ck);
    const float* Al = A_log + j*384 + d*8 + sh;
    float A[4];
    #pragma unroll
    for (int k = 0; k < 4; k++) A[k] = -__expf(Al[k]);
    float P[4] = {1.f,1.f,1.f,1.f}, S[4] = {0.f,0.f,0.f,0.f};
    for (int j2 = 0; j2 < 32; j2++){
      int pp = dir ? (63 - ck*32 - j2) : (ck*32 + j2);
      float dtv = bf2f(sdt[pp][d]);
      float xv  = bf2f(sxc[pp][d]);
      float dx = dtv*xv;
      #pragma unroll
      for (int k = 0; k < 4; k++){
        float dA = __expf(dtv*A[k]);
        P[k] *= dA;
        S[k] = S[k]*dA + dx*bf2f(sbc[pp][sh+k]);
      }
    }
    float* out = PS + ((size_t)g*NCH + c)*768 + d*8 + sh;
    *(float4*)(out)     = make_float4(P[0],P[1],P[2],P[3]);
    *(float4*)(out+384) = make_float4(S[0],S[1],S[2],S[3]);
  }
}

// ---------------------------------------------------------------------------
// Scan phase 2, parallel: 64-lane segment per (g,st) chain; lane owns 16
// chunks; Kogge-Stone affine scan across lanes; replay writes h-at-start.
// ---------------------------------------------------------------------------
extern "C" __global__ void __launch_bounds__(256)
k_scan2(float* __restrict__ PS)
{
  const int t = blockIdx.x*256 + threadIdx.x;
  const int chain = t >> 6;          // 0..1535
  const int lane  = t & 63;
  const int g  = chain / 384;
  const int st = chain % 384;
  float* base = PS + (size_t)g*NCH*768 + st;
  float P[16], S[16];
  const int c0 = lane*16;
  #pragma unroll
  for (int k = 0; k < 16; k++){
    P[k] = base[(size_t)(c0+k)*768];
    S[k] = base[(size_t)(c0+k)*768 + 384];
  }
  float Pl = 1.f, Sl = 0.f;
  #pragma unroll
  for (int k = 0; k < 16; k++){ Sl = P[k]*Sl + S[k]; Pl = P[k]*Pl; }
  float Pi = Pl, Si = Sl;
  #pragma unroll
  for (int off = 1; off < 64; off <<= 1){
    float Pp = __shfl_up(Pi, off);
    float Sp = __shfl_up(Si, off);
    if (lane >= off){ Si = Pi*Sp + Si; Pi = Pi*Pp; }
  }
  float h = __shfl_up(Si, 1);
  if (lane == 0) h = 0.f;
  #pragma unroll
  for (int k = 0; k < 16; k++){
    base[(size_t)(c0+k)*768 + 384] = h;
    h = fmaf(P[k], h, S[k]);
  }
}

// ---------------------------------------------------------------------------
// Scan phase 3 + gate + out-proj + residual, fused. z read from xz buffers.
// ---------------------------------------------------------------------------
extern "C" __global__ void __launch_bounds__(192)
k_scan3c(const ushort_t* __restrict__ dtb, const ushort_t* __restrict__ xcb,
         const ushort_t* __restrict__ xzF, const ushort_t* __restrict__ xzB,
         const ushort_t* __restrict__ BCB,
         const float* __restrict__ A_log, const float* __restrict__ Dp,
         const float* __restrict__ PS, const float* __restrict__ out_w,
         const float* __restrict__ resid, float* __restrict__ outp, int orient)
{
  __shared__ float yf[4][32][49];
  __shared__ float yb[4][32][49];
  const int t = threadIdx.x;
  const int d  = t % 48;
  const int pr = t / 48;
  const int b  = blockIdx.y;
  const int bx = blockIdx.x;
  const int cf = bx*4 + pr;
  const int cbk = NCH-1-cf;

  // ---- fwd (g=b, chunk cf) ----
  {
    const int g = b;
    const float* Al = A_log + (2*orient)*384 + d*8;
    const float* hp = PS + ((size_t)g*NCH + cf)*768 + 384 + d*8;
    float A[8], h[8];
    float4 h0 = *(const float4*)(hp);
    float4 h1 = *(const float4*)(hp+4);
    h[0]=h0.x; h[1]=h0.y; h[2]=h0.z; h[3]=h0.w;
    h[4]=h1.x; h[5]=h1.y; h[6]=h1.z; h[7]=h1.w;
    #pragma unroll
    for (int s = 0; s < 8; s++) A[s] = -__expf(Al[s]);
    const float Dpd = Dp[(2*orient)*48 + d];
    const ushort_t* pdt = dtb + ROW48(g, cf*LC) + d;
    const ushort_t* pxc = xcb + ROW48(g, cf*LC) + d;
    const ushort_t* pz  = xzF + ((size_t)b*LL + cf*LC)*96 + 48 + d;
    const ushort_t* pbc = BCB + ROW16(g, cf*LC);
    for (int j2 = 0; j2 < LC; j2++){
      float dtv = bf2f(pdt[(size_t)j2*48]);
      float xcv = bf2f(pxc[(size_t)j2*48]);
      float zv  = bf2f(pz [(size_t)j2*96]);
      ushort8 br = *(const ushort8*)(pbc + (size_t)j2*16);
      ushort8 cr = *(const ushort8*)(pbc + (size_t)j2*16 + 8);
      float dx = dtv*xcv;
      float y = 0.f;
      #pragma unroll
      for (int s = 0; s < 8; s++){
        float dA = __expf(dtv*A[s]);
        h[s] = h[s]*dA + dx*bf2f(br[s]);
        y += h[s]*bf2f(cr[s]);
      }
      y += xcv*Dpd;
      yf[pr][j2][d] = y * (zv * sigmoidf_(zv));
    }
  }
  // ---- bwd (g=2+b, chunk cbk), output-reversed staging ----
  {
    const int g = 2 + b;
    const float* Al = A_log + (2*orient+1)*384 + d*8;
    const float* hp = PS + ((size_t)g*NCH + cbk)*768 + 384 + d*8;
    float A[8], h[8];
    float4 h0 = *(const float4*)(hp);
    float4 h1 = *(const float4*)(hp+4);
    h[0]=h0.x; h[1]=h0.y; h[2]=h0.z; h[3]=h0.w;
    h[4]=h1.x; h[5]=h1.y; h[6]=h1.z; h[7]=h1.w;
    #pragma unroll
    for (int s = 0; s < 8; s++) A[s] = -__expf(Al[s]);
    const float Dpd = Dp[(2*orient+1)*48 + d];
    const ushort_t* pdt = dtb + ROW48(g, cbk*LC) + d;
    const ushort_t* pxc = xcb + ROW48(g, cbk*LC) + d;
    const ushort_t* pz  = xzB + ((size_t)b*LL + (LL-1-cbk*LC))*96 + 48 + d;
    const ushort_t* pbc = BCB + ROW16(g, cbk*LC);
    for (int j2 = 0; j2 < LC; j2++){
      float dtv = bf2f(pdt[(size_t)j2*48]);
      float xcv = bf2f(pxc[(size_t)j2*48]);
      float zv  = bf2f(*(pz - (size_t)j2*96));
      ushort8 br = *(const ushort8*)(pbc + (size_t)j2*16);
      ushort8 cr = *(const ushort8*)(pbc + (size_t)j2*16 + 8);
      float dx = dtv*xcv;
      float y = 0.f;
      #pragma unroll
      for (int s = 0; s < 8; s++){
        float dA = __expf(dtv*A[s]);
        h[s] = h[s]*dA + dx*bf2f(br[s]);
        y += h[s]*bf2f(cr[s]);
      }
      y += xcv*Dpd;
      yb[pr][31-j2][d] = y * (zv * sigmoidf_(zv));
    }
  }
  __syncthreads();

  // ---- out-proj both dirs + residual, planar write ----
  if (t < 128){
    const int pair = t >> 5, pp = t & 31;
    const int l = bx*128 + t;
    const float* owf = out_w + (size_t)(2*orient)*1152;    // (24,48)
    const float* owb = out_w + (size_t)(2*orient+1)*1152;
    float of[24], ob[24];
    #pragma unroll
    for (int e = 0; e < 24; e++){ of[e]=0.f; ob[e]=0.f; }
    for (int dd = 0; dd < 48; dd++){
      float vf = yf[pair][pp][dd];
      float vb = yb[pair][pp][dd];
      #pragma unroll
      for (int e = 0; e < 24; e++){
        of[e] += vf*owf[e*48+dd];
        ob[e] += vb*owb[e*48+dd];
      }
    }
    const size_t pb = (size_t)b*48*LL + l;
    #pragma unroll
    for (int c2 = 0; c2 < 48; c2++){
      float val = (c2 < 24 ? of[c2] : ob[c2-24]) + resid[pb + (size_t)c2*LL];
      outp[pb + (size_t)c2*LL] = val;
    }
  }
}

// ---------------------------------------------------------------------------
// Digit-rotation transpose: out[t] = in[(t%32)*1024 + (t/32)] per plane,
// optionally + x.
// ---------------------------------------------------------------------------
extern "C" __global__ void __launch_bounds__(256)
k_perm(const float* __restrict__ in, const float* __restrict__ xadd,
       float* __restrict__ out, int addx)
{
  __shared__ float t[32][33];
  const int q = blockIdx.y;            // plane: b*48 + c
  const float* ip = in + (size_t)q*LL;
  float* op = out + (size_t)q*LL;
  const int ab0 = blockIdx.x*32;
  const int tx = threadIdx.x & 31, ty = threadIdx.x >> 5;
  #pragma unroll
  for (int k = 0; k < 4; k++){
    int c = ty + 8*k;
    t[c][tx] = ip[(size_t)c*1024 + ab0 + tx];
  }
  __syncthreads();
  #pragma unroll
  for (int k = 0; k < 4; k++){
    int ab = ty + 8*k;
    float v = t[tx][ab];
    size_t o = (size_t)(ab0+ab)*32 + tx;
    if (addx) v += xadd[(size_t)q*LL + o];
    op[o] = v;
  }
}

extern "C" void kernel_launch(void* const* d_in, const int* in_sizes, int n_in,
                              void* d_out, int out_size, void* d_ws, size_t ws_size,
                              hipStream_t stream)
{
  const float* x       = (const float*)d_in[0];
  const float* ln_g    = (const float*)d_in[1];
  const float* ln_b    = (const float*)d_in[2];
  const float* in_w    = (const float*)d_in[3];
  const float* conv_w  = (const float*)d_in[4];
  const float* conv_b  = (const float*)d_in[5];
  const float* xproj_w = (const float*)d_in[6];
  const float* dt_w    = (const float*)d_in[7];
  const float* dt_b    = (const float*)d_in[8];
  const float* A_log   = (const float*)d_in[9];
  const float* Dp      = (const float*)d_in[10];
  const float* out_w   = (const float*)d_in[11];
  float* out = (float*)d_out;

  char* w = (char*)d_ws;
  ushort_t* dtb  = (ushort_t*)w;  w += (size_t)4*LL*48*2;    // 12.6 MB
  ushort_t* xcb  = (ushort_t*)w;  w += (size_t)4*LL*48*2;    // 12.6 MB
  ushort_t* BCB  = (ushort_t*)w;  w += (size_t)4*LL*16*2;    //  4.2 MB
  ushort_t* xzF  = (ushort_t*)w;  w += (size_t)2*LL*96*2;    // 12.6 MB
  ushort_t* xzB  = (ushort_t*)w;  w += (size_t)2*LL*96*2;    // 12.6 MB
  float*    PS   = (float*)w;     w += (size_t)4*NCH*768*4;  // 12.6 MB
  float*    sout = (float*)w;     w += (size_t)BL48*4;       // 12.6 MB
  float*    curT = (float*)w;     w += (size_t)BL48*4;       // 12.6 MB

  for (int i = 0; i < 3; i++){
    const float* ip;
    if (i == 0) ip = x;
    else {
      k_perm<<<dim3(32, 96), 256, 0, stream>>>(sout, x, curT, 0);
      ip = curT;
    }
    k_inproj<<<dim3(LL/256, 2, 4), 256, 0, stream>>>(ip, ln_g + i*48, ln_b + i*48,
        in_w, xzF, xzB, i);
    k_convscan<<<dim3(LL/64, 2, 2), 192, 0, stream>>>(xzF, xzB, conv_w, conv_b,
        xproj_w, dt_w, dt_b, A_log, dtb, xcb, BCB, PS, i);
    k_scan2<<<dim3(384), 256, 0, stream>>>(PS);
    k_scan3c<<<dim3(NCH/4, 2), 192, 0, stream>>>(dtb, xcb, xzF, xzB, BCB,
        A_log, Dp, PS, out_w, ip, sout, i);
  }
  k_perm<<<dim3(32, 96), 256, 0, stream>>>(sout, x, out, 1);
}